// Round 2
// baseline (2746.221 us; speedup 1.0000x reference)
//
#include <hip/hip_runtime.h>
#include <hip/hip_bf16.h>

typedef __hip_bfloat16 bf16;

static __device__ __forceinline__ float b2f(bf16 x) { return __bfloat162float(x); }
static __device__ __forceinline__ bf16 f2b(float x) { return __float2bfloat16(x); }
static __device__ __forceinline__ float toF(float x) { return x; }
static __device__ __forceinline__ float toF(bf16 x)  { return b2f(x); }
static __device__ __forceinline__ void stor(float* p, float v) { *p = v; }
static __device__ __forceinline__ void stor(bf16* p,  float v) { *p = f2b(v); }

// Generic tiled GEMM:  C[b,m,n] = epi( scale * sum_k A[b,m,k]*B[b,k,n] )
// Strides (in elements) passed explicitly so one kernel serves every layout.
// EPI: 0 = scale + optional per-m bias
//      1 = BN(gamma,beta,mean,var) + LeakyReLU(0.1)       (conv1 fusion)
//      2 = per-m bias + residual add                       (conv3 fusion)
template<int EPI, typename TA, typename TB, typename TC>
__global__ __launch_bounds__(256) void gemm_any(
    const TA* __restrict__ A, const TB* __restrict__ B, TC* __restrict__ C,
    int M, int Nn, int Kd,
    long saM, long saK, long aB,
    long sbK, long sbN, long bB,
    long scM, long scN, long cB,
    float scale,
    const float* __restrict__ bias,
    const float* __restrict__ gamma, const float* __restrict__ beta,
    const float* __restrict__ mean,  const float* __restrict__ var,
    const float* __restrict__ resid, long rB)
{
    __shared__ float As[16][65];   // [k][m], +1 pad
    __shared__ float Bs[16][65];   // [k][n]
    const int b  = blockIdx.z;
    const TA* Ab = A + (long)b * aB;
    const TB* Bb = B + (long)b * bB;
    const int m0 = blockIdx.y * 64, n0 = blockIdx.x * 64;
    const int tid = threadIdx.x;
    const int tx = tid & 15, ty = tid >> 4;
    const bool kfA = (saK == 1);   // pick coalesced load order per layout
    const bool nfB = (sbN == 1);
    float acc[4][4] = {};

    for (int k0 = 0; k0 < Kd; k0 += 16) {
#pragma unroll
        for (int i = 0; i < 4; i++) {
            int idx = tid + i * 256;
            int mm, kk;
            if (kfA) { kk = idx & 15; mm = idx >> 4; }
            else     { mm = idx & 63; kk = idx >> 6; }
            As[kk][mm] = toF(Ab[(long)(m0 + mm) * saM + (long)(k0 + kk) * saK]);
        }
#pragma unroll
        for (int i = 0; i < 4; i++) {
            int idx = tid + i * 256;
            int nn, kk;
            if (nfB) { nn = idx & 63; kk = idx >> 6; }
            else     { kk = idx & 15; nn = idx >> 4; }
            Bs[kk][nn] = toF(Bb[(long)(k0 + kk) * sbK + (long)(n0 + nn) * sbN]);
        }
        __syncthreads();
#pragma unroll
        for (int kk = 0; kk < 16; kk++) {
            float a[4], bb[4];
#pragma unroll
            for (int i = 0; i < 4; i++) a[i]  = As[kk][ty * 4 + i];
#pragma unroll
            for (int j = 0; j < 4; j++) bb[j] = Bs[kk][tx * 4 + j];
#pragma unroll
            for (int i = 0; i < 4; i++)
#pragma unroll
                for (int j = 0; j < 4; j++)
                    acc[i][j] += a[i] * bb[j];
        }
        __syncthreads();
    }

#pragma unroll
    for (int i = 0; i < 4; i++) {
        int m = m0 + ty * 4 + i;
        float add0 = 0.f, mulb = 1.f;
        if (EPI == 1) {
            float g  = gamma[m], be = beta[m];
            float mu = mean[m],  va = var[m];
            mulb = g * rsqrtf(va + 1e-5f);
            add0 = be - mu * mulb;
        } else if (bias) {
            add0 = bias[m];
        }
#pragma unroll
        for (int j = 0; j < 4; j++) {
            int n = n0 + tx * 4 + j;
            float v = acc[i][j] * scale;
            if (EPI == 1) { v = v * mulb + add0; v = v > 0.f ? v : 0.1f * v; }
            else          { v += add0; }
            if (EPI == 2) v += resid[(long)b * rB + (long)m * scM + (long)n * scN];
            stor(&C[(long)b * cB + (long)m * scM + (long)n * scN], v);
        }
    }
}

// Softmax over the P axis (axis=1 of [B,P,N]): one block per (b,n) column.
// 256 threads x 16 values held in registers; in-place S -> probabilities.
__global__ __launch_bounds__(256) void softmax_p_kernel(bf16* __restrict__ S, int P, int N)
{
    const int n = blockIdx.x, b = blockIdx.y;
    const size_t base = ((size_t)b * P) * N + n;
    const int t = threadIdx.x;
    float v[16];
    float mx = -3.4e38f;
#pragma unroll
    for (int i = 0; i < 16; i++) {
        v[i] = b2f(S[base + (size_t)(t + i * 256) * N]);
        mx = fmaxf(mx, v[i]);
    }
    __shared__ float red[16];
#pragma unroll
    for (int o = 32; o > 0; o >>= 1) mx = fmaxf(mx, __shfl_down(mx, o, 64));
    if ((t & 63) == 0) red[t >> 6] = mx;
    __syncthreads();
    mx = fmaxf(fmaxf(red[0], red[1]), fmaxf(red[2], red[3]));
    float s = 0.f;
#pragma unroll
    for (int i = 0; i < 16; i++) { v[i] = __expf(v[i] - mx); s += v[i]; }
#pragma unroll
    for (int o = 32; o > 0; o >>= 1) s += __shfl_down(s, o, 64);
    if ((t & 63) == 0) red[8 + (t >> 6)] = s;
    __syncthreads();
    s = red[8] + red[9] + red[10] + red[11];
    const float inv = 1.f / s;
#pragma unroll
    for (int i = 0; i < 16; i++)
        S[base + (size_t)(t + i * 256) * N] = f2b(v[i] * inv);
}

// 3x3 conv, pad 1, NCHW. Block = 32 output channels x one row (64 px); 256 thr.
__global__ __launch_bounds__(256) void conv3x3_kernel(
    const bf16*  __restrict__ X,   // [B,C,64,64] bf16
    const float* __restrict__ Wt,  // [O,C,3,3]   fp32
    const float* __restrict__ bias,// [O]
    bf16* __restrict__ Y, int C, int Hh, int Wd)
{
    const int KC = 32;
    const int b  = blockIdx.z;
    const int y  = blockIdx.y;
    const int c0 = blockIdx.x * 32;
    __shared__ bf16  xs[32][3][64];      // input slab (3 rows around y)
    __shared__ float wsm[32][32][9];     // [oc][kk][tap]
    const int t  = threadIdx.x;
    const int cl = t >> 3;              // local out-channel 0..31
    const int x0 = (t & 7) * 8;         // 8 consecutive x per thread
    float acc[8] = {};

    for (int k0 = 0; k0 < C; k0 += KC) {
        for (int i = t; i < KC * 3 * 64; i += 256) {
            int x = i & 63; int dy = (i >> 6) % 3; int kk = i / 192;
            int yy = y + dy - 1;
            bf16 val = f2b(0.f);
            if (yy >= 0 && yy < Hh)
                val = X[(((size_t)b * C + k0 + kk) * Hh + yy) * Wd + x];
            xs[kk][dy][x] = val;
        }
        for (int i = t; i < 32 * KC * 9; i += 256) {
            int tap = i % 9; int kk = (i / 9) & 31; int oc = i / 288;
            wsm[oc][kk][tap] = Wt[(((size_t)(c0 + oc) * C) + k0 + kk) * 9 + tap];
        }
        __syncthreads();
        for (int kk = 0; kk < KC; kk++) {
            float w[9];
#pragma unroll
            for (int q = 0; q < 9; q++) w[q] = wsm[cl][kk][q];
#pragma unroll
            for (int dy = 0; dy < 3; dy++) {
                float h[10];
#pragma unroll
                for (int q = 0; q < 10; q++) {
                    int x = x0 + q - 1;
                    h[q] = (x >= 0 && x < 64) ? b2f(xs[kk][dy][x]) : 0.f;
                }
#pragma unroll
                for (int xi = 0; xi < 8; xi++)
                    acc[xi] += w[dy*3+0]*h[xi] + w[dy*3+1]*h[xi+1] + w[dy*3+2]*h[xi+2];
            }
        }
        __syncthreads();
    }
    const float bb = bias[c0 + cl];
    for (int xi = 0; xi < 8; xi++)
        Y[(((size_t)b * C + c0 + cl) * Hh + y) * Wd + x0 + xi] = f2b(acc[xi] + bb);
}

extern "C" void kernel_launch(void* const* d_in, const int* in_sizes, int n_in,
                              void* d_out, int out_size, void* d_ws, size_t ws_size,
                              hipStream_t stream)
{
    const float* graph = (const float*)d_in[0];   // [8,1024,32]
    const float* image = (const float*)d_in[1];   // [8,256,64,64]
    const float* Wq  = (const float*)d_in[2];
    const float* bq  = (const float*)d_in[3];
    const float* Wk  = (const float*)d_in[4];
    const float* bk  = (const float*)d_in[5];
    const float* Wv  = (const float*)d_in[6];
    const float* bv  = (const float*)d_in[7];
    const float* c1w = (const float*)d_in[8];
    const float* gam = (const float*)d_in[9];
    const float* bet = (const float*)d_in[10];
    const float* mea = (const float*)d_in[11];
    const float* var = (const float*)d_in[12];
    const float* c2w = (const float*)d_in[13];
    const float* c2b = (const float*)d_in[14];
    const float* c3w = (const float*)d_in[15];
    const float* c3b = (const float*)d_in[16];
    float* out = (float*)d_out;

    const int B = 8, C = 256, Hh = 64, Wd = 64, P = 4096, N = 1024, G = 32;
    char* ws = (char*)d_ws;
    const size_t MiB = 1024 * 1024;
    bf16* Kbuf = (bf16*)(ws);                 // B*C*N  bf16  (4 MiB)
    bf16* Vbuf = (bf16*)(ws + 4  * MiB);      // B*C*N  bf16  (4 MiB)
    bf16* Qbuf = (bf16*)(ws + 8  * MiB);      // B*C*P  bf16 (16 MiB) -> reused as msg
    bf16* Sbuf = (bf16*)(ws + 24 * MiB);      // B*P*N  bf16 (64 MiB) -> reused as h1,h2
    bf16* Mbuf = Qbuf;                        // msg overwrites Q (dead after S)
    bf16* H1   = Sbuf;                        // h1 overwrites S (dead after msg)
    bf16* H2   = (bf16*)(ws + 40 * MiB);      // h2 in S-slot + 16 MiB
    // peak workspace: 88 MiB

    // 1) K[b,c,n] = sum_g Wk[c,g]*graph[b,n,g] + bk[c]
    gemm_any<0, float, float, bf16><<<dim3(N/64, C/64, B), 256, 0, stream>>>(
        Wk, graph, Kbuf, C, N, G,
        G, 1, 0,     1, G, (long)N*G,     N, 1, (long)C*N,
        1.f, bk, nullptr, nullptr, nullptr, nullptr, nullptr, 0);
    // 2) V
    gemm_any<0, float, float, bf16><<<dim3(N/64, C/64, B), 256, 0, stream>>>(
        Wv, graph, Vbuf, C, N, G,
        G, 1, 0,     1, G, (long)N*G,     N, 1, (long)C*N,
        1.f, bv, nullptr, nullptr, nullptr, nullptr, nullptr, 0);
    // 3) Q[b,c,p] = sum_k Wq[c,k]*x[b,k,p] + bq[c]
    gemm_any<0, float, float, bf16><<<dim3(P/64, C/64, B), 256, 0, stream>>>(
        Wq, image, Qbuf, C, P, C,
        C, 1, 0,     P, 1, (long)C*P,     P, 1, (long)C*P,
        1.f, bq, nullptr, nullptr, nullptr, nullptr, nullptr, 0);
    // 4) S[b,p,n] = (1/16) * sum_c Q[b,c,p]*K[b,c,n]
    gemm_any<0, bf16, bf16, bf16><<<dim3(N/64, P/64, B), 256, 0, stream>>>(
        Qbuf, Kbuf, Sbuf, P, N, C,
        1, P, (long)C*P,     N, 1, (long)C*N,     N, 1, (long)P*N,
        0.0625f, nullptr, nullptr, nullptr, nullptr, nullptr, nullptr, 0);
    // 5) softmax over p per (b,n), in place
    softmax_p_kernel<<<dim3(N, B), 256, 0, stream>>>(Sbuf, P, N);
    // 6) msg[b,c,p] = sum_n V[b,c,n]*att[b,p,n]   (into Q's slot)
    gemm_any<0, bf16, bf16, bf16><<<dim3(P/64, C/64, B), 256, 0, stream>>>(
        Vbuf, Sbuf, Mbuf, C, P, N,
        N, 1, (long)C*N,     1, N, (long)P*N,     P, 1, (long)C*P,
        1.f, nullptr, nullptr, nullptr, nullptr, nullptr, nullptr, 0);
    // 7) h1 = LeakyReLU(BN(conv1(msg)))   (into S's slot; S dead)
    gemm_any<1, float, bf16, bf16><<<dim3(P/64, C/64, B), 256, 0, stream>>>(
        c1w, Mbuf, H1, C, P, C,
        C, 1, 0,     P, 1, (long)C*P,     P, 1, (long)C*P,
        1.f, nullptr, gam, bet, mea, var, nullptr, 0);
    // 8) h2 = conv2 3x3 pad1 + b
    conv3x3_kernel<<<dim3(C/32, Hh, B), 256, 0, stream>>>(H1, c2w, c2b, H2, C, Hh, Wd);
    // 9) out = image + conv3(h2) + b
    gemm_any<2, float, bf16, float><<<dim3(P/64, C/64, B), 256, 0, stream>>>(
        c3w, H2, out, C, P, C,
        C, 1, 0,     P, 1, (long)C*P,     P, 1, (long)C*P,
        1.f, c3b, nullptr, nullptr, nullptr, nullptr, image, (long)C*P);
}

// Round 5
// 1570.009 us; speedup vs baseline: 1.7492x; 1.7492x over previous
//
#include <hip/hip_runtime.h>
#include <hip/hip_bf16.h>

typedef __hip_bfloat16 bf16;
typedef unsigned short u16;
typedef __attribute__((ext_vector_type(8))) short  b8v;    // 8 bf16 bits (4 VGPR) MFMA operand
typedef __attribute__((ext_vector_type(8))) unsigned short u16x8;
typedef __attribute__((ext_vector_type(4))) unsigned short u16x4;
typedef __attribute__((ext_vector_type(4))) float f32x4;

static __device__ __forceinline__ float us2f(u16 s) {
    unsigned int u = ((unsigned int)s) << 16;
    return __builtin_bit_cast(float, u);
}
static __device__ __forceinline__ u16 f2us(float x) {
    union { bf16 h; u16 s; } v; v.h = __float2bfloat16(x); return v.s;
}
static __device__ __forceinline__ float b2f(bf16 x) { return __bfloat162float(x); }
static __device__ __forceinline__ bf16 f2b(float x) { return __float2bfloat16(x); }
static __device__ __forceinline__ float toF(float x) { return x; }
static __device__ __forceinline__ float toF(bf16 x)  { return b2f(x); }
static __device__ __forceinline__ void stor(float* p, float v) { *p = v; }
static __device__ __forceinline__ void stor(bf16* p,  float v) { *p = f2b(v); }

// ---------------- small prep kernels ----------------

__global__ __launch_bounds__(256) void cast_f2b4(const float* __restrict__ src,
                                                 u16* __restrict__ dst, int n4)
{
    int i = blockIdx.x * 256 + threadIdx.x;
    if (i < n4) {
        float4 v = ((const float4*)src)[i];
        u16x4 o = { f2us(v.x), f2us(v.y), f2us(v.z), f2us(v.w) };
        ((u16x4*)dst)[i] = o;
    }
}

// x[b][c][p] f32 -> xT[b][p][c] bf16, 64x64 LDS tiles
// row stride 72 u16 = 144 B keeps the u16x8 (ds_read_b128) reads 16B-aligned
__global__ __launch_bounds__(256) void transpose_cast_x(const float* __restrict__ x,
                                                        u16* __restrict__ xT, int C, int P)
{
    __shared__ u16 t[64][72];
    const int b = blockIdx.z, c0 = blockIdx.y * 64, p0 = blockIdx.x * 64;
    const int tid = threadIdx.x;
    const int r = tid >> 2, q = tid & 3;
    const float* src = x + ((size_t)b * C + c0 + r) * P + p0 + q * 16;
#pragma unroll
    for (int i = 0; i < 16; i++) t[q * 16 + i][r] = f2us(src[i]);
    __syncthreads();
    u16* dst = xT + ((size_t)b * P + p0 + r) * C + c0 + q * 16;
    *(u16x8*)dst       = *(u16x8*)&t[r][q * 16];
    *(u16x8*)(dst + 8) = *(u16x8*)&t[r][q * 16 + 8];
}

// ---------------- fp32-input VALU GEMM (tiny K/V projections only) ----------------
// EPI: 0 bias per m; 3 bias per n
template<int EPI, typename TA, typename TB, typename TC>
__global__ __launch_bounds__(256) void gemm_any(
    const TA* __restrict__ A, const TB* __restrict__ B, TC* __restrict__ C,
    int M, int Nn, int Kd,
    long saM, long saK, long aB,
    long sbK, long sbN, long bB,
    long scM, long scN, long cB,
    float scale, const float* __restrict__ bias)
{
    __shared__ float As[16][65];
    __shared__ float Bs[16][65];
    const int b  = blockIdx.z;
    const TA* Ab = A + (long)b * aB;
    const TB* Bb = B + (long)b * bB;
    const int m0 = blockIdx.y * 64, n0 = blockIdx.x * 64;
    const int tid = threadIdx.x;
    const int tx = tid & 15, ty = tid >> 4;
    const bool kfA = (saK == 1);
    const bool nfB = (sbN == 1);
    float acc[4][4] = {};

    for (int k0 = 0; k0 < Kd; k0 += 16) {
#pragma unroll
        for (int i = 0; i < 4; i++) {
            int idx = tid + i * 256; int mm, kk;
            if (kfA) { kk = idx & 15; mm = idx >> 4; }
            else     { mm = idx & 63; kk = idx >> 6; }
            As[kk][mm] = toF(Ab[(long)(m0 + mm) * saM + (long)(k0 + kk) * saK]);
        }
#pragma unroll
        for (int i = 0; i < 4; i++) {
            int idx = tid + i * 256; int nn, kk;
            if (nfB) { nn = idx & 63; kk = idx >> 6; }
            else     { kk = idx & 15; nn = idx >> 4; }
            Bs[kk][nn] = toF(Bb[(long)(k0 + kk) * sbK + (long)(n0 + nn) * sbN]);
        }
        __syncthreads();
#pragma unroll
        for (int kk = 0; kk < 16; kk++) {
            float a[4], bb[4];
#pragma unroll
            for (int i = 0; i < 4; i++) a[i]  = As[kk][ty * 4 + i];
#pragma unroll
            for (int j = 0; j < 4; j++) bb[j] = Bs[kk][tx * 4 + j];
#pragma unroll
            for (int i = 0; i < 4; i++)
#pragma unroll
                for (int j = 0; j < 4; j++) acc[i][j] += a[i] * bb[j];
        }
        __syncthreads();
    }
#pragma unroll
    for (int i = 0; i < 4; i++) {
        int m = m0 + ty * 4 + i;
        float add0 = (EPI == 0 && bias) ? bias[m] : 0.f;
#pragma unroll
        for (int j = 0; j < 4; j++) {
            int n = n0 + tx * 4 + j;
            float v = acc[i][j] * scale + add0;
            if (EPI == 3 && bias) v += bias[n];
            stor(&C[(long)b * cB + (long)m * scM + (long)n * scN], v);
        }
    }
}

// ---------------- MFMA GEMM: C[m][n] = epi( scale * sum_k A[m][k] * Bt[n][k] ) ----------------
// A: [M][lda] k-contiguous bf16-bits. Bt: [N][ldb] k-contiguous bf16-bits.
// CT=false: C[m*ldc+n]; CT=true: C[n*ldc+m] (packed 4-wide m stores).
// EPI: 0 = scale + optional bias[m]; 1 = BN+LeakyReLU(0.1); 2 = bias[m] + resid (fp32 out)
template<int EPI, bool CT, typename TC>
__global__ __launch_bounds__(256) void gemm_mfma(
    const u16* __restrict__ A, const u16* __restrict__ Bt, TC* __restrict__ Cc,
    int M, int N, int K, int lda, int ldb, int ldc,
    long aBat, long bBat, long cBat,
    float scale, const float* __restrict__ bias,
    const float* __restrict__ gamma, const float* __restrict__ beta,
    const float* __restrict__ mean,  const float* __restrict__ var,
    const float* __restrict__ resid, long rBat, int ldr)
{
    __shared__ u16 Al[128][40];   // [m][k], +8 pad (80 B row stride, 16B-aligned)
    __shared__ u16 Bl[128][40];   // [n][k]
    const int bat = blockIdx.z;
    const int m0 = blockIdx.y * 128, n0 = blockIdx.x * 128;
    const int tid = threadIdx.x;
    const int lane = tid & 63, wid = tid >> 6;
    const int wr = wid >> 1, wc = wid & 1;      // 2x2 wave grid, 64x64 per wave
    const int fr = lane & 15, fq = lane >> 4;
    const int sr = tid >> 1, sh = (tid & 1) * 16;   // 2 threads/row, 16 k-cols each

    const u16* Ab = A  + (size_t)bat * aBat + (size_t)(m0 + sr) * lda + sh;
    const u16* Bb = Bt + (size_t)bat * bBat + (size_t)(n0 + sr) * ldb + sh;

    f32x4 acc[4][4];
#pragma unroll
    for (int i = 0; i < 4; i++)
#pragma unroll
        for (int j = 0; j < 4; j++) acc[i][j] = (f32x4){0.f, 0.f, 0.f, 0.f};

    for (int k0 = 0; k0 < K; k0 += 32) {
        // full 16-element span per thread (2 x u16x8) — 2 threads cover a 32-k row
        u16x8 av0 = *(const u16x8*)(Ab + k0);
        u16x8 av1 = *(const u16x8*)(Ab + k0 + 8);
        u16x8 bv0 = *(const u16x8*)(Bb + k0);
        u16x8 bv1 = *(const u16x8*)(Bb + k0 + 8);
        *(u16x8*)&Al[sr][sh]     = av0;
        *(u16x8*)&Al[sr][sh + 8] = av1;
        *(u16x8*)&Bl[sr][sh]     = bv0;
        *(u16x8*)&Bl[sr][sh + 8] = bv1;
        __syncthreads();
        b8v a[4], b[4];
#pragma unroll
        for (int mi = 0; mi < 4; mi++) a[mi] = *(const b8v*)&Al[wr * 64 + mi * 16 + fr][fq * 8];
#pragma unroll
        for (int ni = 0; ni < 4; ni++) b[ni] = *(const b8v*)&Bl[wc * 64 + ni * 16 + fr][fq * 8];
#pragma unroll
        for (int mi = 0; mi < 4; mi++)
#pragma unroll
            for (int ni = 0; ni < 4; ni++)
                acc[mi][ni] = __builtin_amdgcn_mfma_f32_16x16x32_bf16(a[mi], b[ni], acc[mi][ni], 0, 0, 0);
        __syncthreads();
    }

    const int mbase = m0 + wr * 64, nbase = n0 + wc * 64;
#pragma unroll
    for (int mi = 0; mi < 4; mi++) {
        float esc[4], ead[4];
#pragma unroll
        for (int j = 0; j < 4; j++) {
            int m = mbase + mi * 16 + fq * 4 + j;
            if (EPI == 1) {
                float sc = gamma[m] * rsqrtf(var[m] + 1e-5f);
                esc[j] = sc; ead[j] = beta[m] - mean[m] * sc;
            } else {
                esc[j] = scale; ead[j] = bias ? bias[m] : 0.f;
            }
        }
#pragma unroll
        for (int ni = 0; ni < 4; ni++) {
            f32x4 v = acc[mi][ni];
            const int n = nbase + ni * 16 + fr;
            if (CT) {
                const int mb = mbase + mi * 16 + fq * 4;
                u16x4 pk;
#pragma unroll
                for (int j = 0; j < 4; j++) {
                    float x = v[j] * esc[j] + ead[j];
                    if (EPI == 1) x = x > 0.f ? x : 0.1f * x;
                    pk[j] = f2us(x);
                }
                *(u16x4*)((u16*)Cc + (size_t)bat * cBat + (size_t)n * ldc + mb) = pk;
            } else {
#pragma unroll
                for (int j = 0; j < 4; j++) {
                    int m = mbase + mi * 16 + fq * 4 + j;
                    float x = v[j] * esc[j] + ead[j];
                    if (EPI == 1) x = x > 0.f ? x : 0.1f * x;
                    if (EPI == 2) x += resid[(size_t)bat * rBat + (size_t)m * ldr + n];
                    TC* p = Cc + (size_t)bat * cBat + (size_t)m * ldc + n;
                    if constexpr (sizeof(TC) == 2) *(u16*)p = f2us(x); else *(float*)p = x;
                }
            }
        }
    }
}

// ---------------- conv2 3x3 pad1 as implicit MFMA GEMM (K = C*9 = 2304) ----------------
// A = w2 [256][2304] bf16-bits; X = h1 [B][256][4096]; Y = h2T [B][4096][256]
__global__ __launch_bounds__(256) void conv3x3_mfma(
    const u16* __restrict__ Wt, const u16* __restrict__ X, u16* __restrict__ Y,
    const float* __restrict__ bias)
{
    const int C = 256, P = 4096, K = 2304;
    __shared__ u16 Al[128][40];
    __shared__ u16 Bl[128][40];
    const int bat = blockIdx.z;
    const int m0 = blockIdx.y * 128, n0 = blockIdx.x * 128;
    const int tid = threadIdx.x;
    const int lane = tid & 63, wid = tid >> 6;
    const int wr = wid >> 1, wc = wid & 1;
    const int fr = lane & 15, fq = lane >> 4;
    const int sr = tid >> 1, sh = (tid & 1) * 16;
    const int kk = tid >> 3, ns = tid & 7;

    const u16* Ab = Wt + (size_t)(m0 + sr) * K + sh;
    const u16* Xb = X + (size_t)bat * C * P;

    f32x4 acc[4][4];
#pragma unroll
    for (int i = 0; i < 4; i++)
#pragma unroll
        for (int j = 0; j < 4; j++) acc[i][j] = (f32x4){0.f, 0.f, 0.f, 0.f};

    for (int k0 = 0; k0 < K; k0 += 32) {
        u16x8 av0 = *(const u16x8*)(Ab + k0);
        u16x8 av1 = *(const u16x8*)(Ab + k0 + 8);
        *(u16x8*)&Al[sr][sh]     = av0;
        *(u16x8*)&Al[sr][sh + 8] = av1;
        const int k = k0 + kk;
        const int c = k / 9, tap = k - 9 * c;
        const int dy = tap / 3 - 1, dx = tap - (tap / 3) * 3 - 1;
        const u16* slab = Xb + (size_t)c * P;
#pragma unroll
        for (int i = 0; i < 16; i++) {
            int n = ns + i * 8;
            int p = n0 + n;
            int y = (p >> 6) + dy, x = (p & 63) + dx;
            u16 v = 0;
            if ((unsigned)y < 64u && (unsigned)x < 64u) v = slab[y * 64 + x];
            Bl[n][kk] = v;
        }
        __syncthreads();
        b8v a[4], b[4];
#pragma unroll
        for (int mi = 0; mi < 4; mi++) a[mi] = *(const b8v*)&Al[wr * 64 + mi * 16 + fr][fq * 8];
#pragma unroll
        for (int ni = 0; ni < 4; ni++) b[ni] = *(const b8v*)&Bl[wc * 64 + ni * 16 + fr][fq * 8];
#pragma unroll
        for (int mi = 0; mi < 4; mi++)
#pragma unroll
            for (int ni = 0; ni < 4; ni++)
                acc[mi][ni] = __builtin_amdgcn_mfma_f32_16x16x32_bf16(a[mi], b[ni], acc[mi][ni], 0, 0, 0);
        __syncthreads();
    }

    const int mbase = m0 + wr * 64, nbase = n0 + wc * 64;
#pragma unroll
    for (int mi = 0; mi < 4; mi++) {
        const int mb = mbase + mi * 16 + fq * 4;
        float bb[4];
#pragma unroll
        for (int j = 0; j < 4; j++) bb[j] = bias[mb + j];
#pragma unroll
        for (int ni = 0; ni < 4; ni++) {
            const int n = nbase + ni * 16 + fr;
            u16x4 pk;
#pragma unroll
            for (int j = 0; j < 4; j++) pk[j] = f2us(acc[mi][ni][j] + bb[j]);
            *(u16x4*)&Y[(size_t)bat * P * C + (size_t)n * C + mb] = pk;
        }
    }
}

// ---------------- softmax over P per (b,n), two coalesced passes ----------------
__global__ __launch_bounds__(256) void softmax_pass1(const u16* __restrict__ S,
                                                     float2* __restrict__ st, int P, int N)
{
    const int n = blockIdx.x * 256 + threadIdx.x;
    const int b = blockIdx.y;
    const u16* col = S + (size_t)b * P * N + n;
    float m = -3.4e38f, s = 0.f;
    for (int p = 0; p < P; p++) {
        float v = us2f(col[(size_t)p * N]);
        float mn = fmaxf(m, v);
        s = s * __expf(m - mn) + __expf(v - mn);
        m = mn;
    }
    st[(size_t)b * N + n] = make_float2(m, 1.f / s);
}

__global__ __launch_bounds__(256) void softmax_pass2(u16* __restrict__ S,
                                                     const float2* __restrict__ st, int P, int N)
{
    const size_t idx = ((size_t)blockIdx.x * 256 + threadIdx.x) * 8;
    const int n0 = (int)(idx % N);
    const size_t bp = idx / N;
    const int b = (int)(bp / P);
    const float2* sb = st + (size_t)b * N;
    u16x8 v = *(u16x8*)&S[idx];
#pragma unroll
    for (int j = 0; j < 8; j++) {
        float2 ms = sb[n0 + j];
        v[j] = f2us(__expf(us2f(v[j]) - ms.x) * ms.y);
    }
    *(u16x8*)&S[idx] = v;
}

// ---------------- launch ----------------
// Workspace plan — everything inside [0, 88 MiB):
//   [ 0,64)  S [B][P][N]          (written by S-gemm, read softmax+msg)
//   [ 0,16)  xT alias             (dead before S written)
//   [16,16.125) Wq_b alias        (dead before S written)
//   [64,80)  Qt -> msgT           (Qt dead after S-gemm)
//   [80,84)  Kt -> {st, c1/c3/c2 bf16 weights}  (Kt dead after S-gemm)
//   [84,88)  Vb                   (dead after msg-gemm)
//   [ 0,16)  h1  (S dead after msg-gemm);  [16,32) h2T

extern "C" void kernel_launch(void* const* d_in, const int* in_sizes, int n_in,
                              void* d_out, int out_size, void* d_ws, size_t ws_size,
                              hipStream_t stream)
{
    const float* graph = (const float*)d_in[0];   // [8,1024,32]
    const float* image = (const float*)d_in[1];   // [8,256,64,64]
    const float* Wq  = (const float*)d_in[2];
    const float* bq  = (const float*)d_in[3];
    const float* Wk  = (const float*)d_in[4];
    const float* bk  = (const float*)d_in[5];
    const float* Wv  = (const float*)d_in[6];
    const float* bv  = (const float*)d_in[7];
    const float* c1w = (const float*)d_in[8];
    const float* gam = (const float*)d_in[9];
    const float* bet = (const float*)d_in[10];
    const float* mea = (const float*)d_in[11];
    const float* var = (const float*)d_in[12];
    const float* c2w = (const float*)d_in[13];
    const float* c2b = (const float*)d_in[14];
    const float* c3w = (const float*)d_in[15];
    const float* c3b = (const float*)d_in[16];
    float* out = (float*)d_out;

    const int B = 8, C = 256, P = 4096, N = 1024, G = 32;
    const size_t MiB = 1024 * 1024, KiB = 1024;
    char* ws = (char*)d_ws;
    u16* S     = (u16*)(ws);                        // [0,64) MiB
    u16* xT    = (u16*)(ws);                        // alias [0,16)
    u16* Wq_b  = (u16*)(ws + 16 * MiB);             // alias [16,16.125)
    u16* Qt    = (u16*)(ws + 64 * MiB);             // [64,80)
    u16* msgT  = Qt;                                // reuse after S-gemm
    float2* st = (float2*)(ws + 80 * MiB);          // 64 KiB (Kt slot, post S-gemm)
    u16* c1w_b = (u16*)(ws + 80 * MiB + 64 * KiB);  // 128 KiB
    u16* c3w_b = (u16*)(ws + 80 * MiB + 192 * KiB); // 128 KiB
    u16* c2w_b = (u16*)(ws + 80 * MiB + 320 * KiB); // 1.125 MiB (< 84 MiB)
    u16* Kt    = (u16*)(ws + 80 * MiB);             // [80,84), dead after S-gemm
    u16* Vb    = (u16*)(ws + 84 * MiB);             // [84,88)
    u16* h1    = (u16*)(ws);                        // [0,16), S dead after msg
    u16* h2T   = (u16*)(ws + 16 * MiB);             // [16,32)

    // prep
    transpose_cast_x<<<dim3(P / 64, C / 64, B), 256, 0, stream>>>(image, xT, C, P);
    cast_f2b4<<<64,  256, 0, stream>>>(Wq,  Wq_b,  16384);
    // K-proj: Kt[b][n][c] = sum_g graph[b][n][g]*Wk[c][g] + bk[c]
    gemm_any<3, float, float, bf16><<<dim3(C / 64, N / 64, B), 256, 0, stream>>>(
        graph, Wk, (bf16*)Kt, N, C, G,
        G, 1, (long)N * G,   1, G, 0,   C, 1, (long)N * C, 1.f, bk);
    // V-proj: Vb[b][c][n] = sum_g Wv[c][g]*graph[b][n][g] + bv[c]
    gemm_any<0, float, float, bf16><<<dim3(N / 64, C / 64, B), 256, 0, stream>>>(
        Wv, graph, (bf16*)Vb, C, N, G,
        G, 1, 0,   1, G, (long)N * G,   N, 1, (long)C * N, 1.f, bv);

    // Q: Qt[b][p][c] = sum_k Wq[c][k]*xT[b][p][k] + bq[c]    (CT store)
    gemm_mfma<0, true, u16><<<dim3(P / 128, C / 128, B), 256, 0, stream>>>(
        Wq_b, xT, Qt, C, P, C, C, C, C,
        0, (long)P * C, (long)P * C, 1.f, bq,
        nullptr, nullptr, nullptr, nullptr, nullptr, 0, 0);
    // S[b][p][n] = (1/16) sum_c Qt[p][c]*Kt[n][c]
    gemm_mfma<0, false, u16><<<dim3(N / 128, P / 128, B), 256, 0, stream>>>(
        Qt, Kt, S, P, N, C, C, C, N,
        (long)P * C, (long)N * C, (long)P * N, 0.0625f, nullptr,
        nullptr, nullptr, nullptr, nullptr, nullptr, 0, 0);
    // Kt slot now dead: cast conv weights into it
    cast_f2b4<<<64,  256, 0, stream>>>(c1w, c1w_b, 16384);
    cast_f2b4<<<64,  256, 0, stream>>>(c3w, c3w_b, 16384);
    cast_f2b4<<<576, 256, 0, stream>>>(c2w, c2w_b, 147456);
    // softmax over p
    softmax_pass1<<<dim3(N / 256, B), 256, 0, stream>>>(S, st, P, N);
    softmax_pass2<<<dim3((int)(((size_t)B * P * N / 8) / 256)), 256, 0, stream>>>(S, st, P, N);
    // msgT[b][p][c] = sum_n Vb[c][n]*att[p][n]   (CT store, into Qt slot)
    gemm_mfma<0, true, u16><<<dim3(P / 128, C / 128, B), 256, 0, stream>>>(
        Vb, S, msgT, C, P, N, N, N, C,
        (long)C * N, (long)P * N, (long)P * C, 1.f, nullptr,
        nullptr, nullptr, nullptr, nullptr, nullptr, 0, 0);
    // h1[b][c][p] = LeakyReLU(BN(conv1(msg)))   (into S slot [0,16))
    gemm_mfma<1, false, u16><<<dim3(P / 128, C / 128, B), 256, 0, stream>>>(
        c1w_b, msgT, h1, C, P, C, C, C, P,
        0, (long)P * C, (long)C * P, 1.f, nullptr,
        gam, bet, mea, var, nullptr, 0, 0);
    // h2T[b][p][c] = conv2 3x3(h1) + c2b   (into S slot [16,32))
    conv3x3_mfma<<<dim3(P / 128, C / 128, B), 256, 0, stream>>>(c2w_b, h1, h2T, c2b);
    // out[b][c][p] = image + conv3(h2) + c3b
    gemm_mfma<2, false, float><<<dim3(P / 128, C / 128, B), 256, 0, stream>>>(
        c3w_b, h2T, out, C, P, C, C, C, P,
        0, (long)P * C, (long)C * P, 1.f, c3b,
        nullptr, nullptr, nullptr, nullptr, image, (long)C * P, P);
}

// Round 6
// 412.718 us; speedup vs baseline: 6.6540x; 3.8041x over previous
//
#include <hip/hip_runtime.h>
#include <hip/hip_bf16.h>

typedef __hip_bfloat16 bf16;
typedef unsigned short u16;
typedef __attribute__((ext_vector_type(8))) short  b8v;    // 8 bf16 bits (4 VGPR) MFMA operand
typedef __attribute__((ext_vector_type(8))) unsigned short u16x8;
typedef __attribute__((ext_vector_type(4))) unsigned short u16x4;
typedef __attribute__((ext_vector_type(4))) float f32x4;

static __device__ __forceinline__ float us2f(u16 s) {
    unsigned int u = ((unsigned int)s) << 16;
    return __builtin_bit_cast(float, u);
}
static __device__ __forceinline__ u16 f2us(float x) {
    union { bf16 h; u16 s; } v; v.h = __float2bfloat16(x); return v.s;
}
static __device__ __forceinline__ float b2f(bf16 x) { return __bfloat162float(x); }
static __device__ __forceinline__ bf16 f2b(float x) { return __float2bfloat16(x); }
static __device__ __forceinline__ float toF(float x) { return x; }
static __device__ __forceinline__ float toF(bf16 x)  { return b2f(x); }
static __device__ __forceinline__ void stor(float* p, float v) { *p = v; }
static __device__ __forceinline__ void stor(bf16* p,  float v) { *p = f2b(v); }

// ---------------- small prep kernels ----------------

__global__ __launch_bounds__(256) void cast_f2b4(const float* __restrict__ src,
                                                 u16* __restrict__ dst, int n4)
{
    int i = blockIdx.x * 256 + threadIdx.x;
    if (i < n4) {
        float4 v = ((const float4*)src)[i];
        u16x4 o = { f2us(v.x), f2us(v.y), f2us(v.z), f2us(v.w) };
        ((u16x4*)dst)[i] = o;
    }
}

// x[b][c][p] f32 -> xT[b][p][c] bf16, 64x64 LDS tiles
// row stride 72 u16 = 144 B keeps the u16x8 (ds_read_b128) reads 16B-aligned
__global__ __launch_bounds__(256) void transpose_cast_x(const float* __restrict__ x,
                                                        u16* __restrict__ xT, int C, int P)
{
    __shared__ u16 t[64][72];
    const int b = blockIdx.z, c0 = blockIdx.y * 64, p0 = blockIdx.x * 64;
    const int tid = threadIdx.x;
    const int r = tid >> 2, q = tid & 3;
    const float* src = x + ((size_t)b * C + c0 + r) * P + p0 + q * 16;
#pragma unroll
    for (int i = 0; i < 16; i++) t[q * 16 + i][r] = f2us(src[i]);
    __syncthreads();
    u16* dst = xT + ((size_t)b * P + p0 + r) * C + c0 + q * 16;
    *(u16x8*)dst       = *(u16x8*)&t[r][q * 16];
    *(u16x8*)(dst + 8) = *(u16x8*)&t[r][q * 16 + 8];
}

// ---------------- fp32-input VALU GEMM (tiny K/V projections only) ----------------
// EPI: 0 bias per m; 3 bias per n
template<int EPI, typename TA, typename TB, typename TC>
__global__ __launch_bounds__(256) void gemm_any(
    const TA* __restrict__ A, const TB* __restrict__ B, TC* __restrict__ C,
    int M, int Nn, int Kd,
    long saM, long saK, long aB,
    long sbK, long sbN, long bB,
    long scM, long scN, long cB,
    float scale, const float* __restrict__ bias)
{
    __shared__ float As[16][65];
    __shared__ float Bs[16][65];
    const int b  = blockIdx.z;
    const TA* Ab = A + (long)b * aB;
    const TB* Bb = B + (long)b * bB;
    const int m0 = blockIdx.y * 64, n0 = blockIdx.x * 64;
    const int tid = threadIdx.x;
    const int tx = tid & 15, ty = tid >> 4;
    const bool kfA = (saK == 1);
    const bool nfB = (sbN == 1);
    float acc[4][4] = {};

    for (int k0 = 0; k0 < Kd; k0 += 16) {
#pragma unroll
        for (int i = 0; i < 4; i++) {
            int idx = tid + i * 256; int mm, kk;
            if (kfA) { kk = idx & 15; mm = idx >> 4; }
            else     { mm = idx & 63; kk = idx >> 6; }
            As[kk][mm] = toF(Ab[(long)(m0 + mm) * saM + (long)(k0 + kk) * saK]);
        }
#pragma unroll
        for (int i = 0; i < 4; i++) {
            int idx = tid + i * 256; int nn, kk;
            if (nfB) { nn = idx & 63; kk = idx >> 6; }
            else     { kk = idx & 15; nn = idx >> 4; }
            Bs[kk][nn] = toF(Bb[(long)(k0 + kk) * sbK + (long)(n0 + nn) * sbN]);
        }
        __syncthreads();
#pragma unroll
        for (int kk = 0; kk < 16; kk++) {
            float a[4], bb[4];
#pragma unroll
            for (int i = 0; i < 4; i++) a[i]  = As[kk][ty * 4 + i];
#pragma unroll
            for (int j = 0; j < 4; j++) bb[j] = Bs[kk][tx * 4 + j];
#pragma unroll
            for (int i = 0; i < 4; i++)
#pragma unroll
                for (int j = 0; j < 4; j++) acc[i][j] += a[i] * bb[j];
        }
        __syncthreads();
    }
#pragma unroll
    for (int i = 0; i < 4; i++) {
        int m = m0 + ty * 4 + i;
        float add0 = (EPI == 0 && bias) ? bias[m] : 0.f;
#pragma unroll
        for (int j = 0; j < 4; j++) {
            int n = n0 + tx * 4 + j;
            float v = acc[i][j] * scale + add0;
            if (EPI == 3 && bias) v += bias[n];
            stor(&C[(long)b * cB + (long)m * scM + (long)n * scN], v);
        }
    }
}

// ---------------- MFMA GEMM: C[m][n] = epi( scale * sum_k A[m][k] * Bt[n][k] ) ----------------
template<int EPI, bool CT, typename TC>
__global__ __launch_bounds__(256) void gemm_mfma(
    const u16* __restrict__ A, const u16* __restrict__ Bt, TC* __restrict__ Cc,
    int M, int N, int K, int lda, int ldb, int ldc,
    long aBat, long bBat, long cBat,
    float scale, const float* __restrict__ bias,
    const float* __restrict__ gamma, const float* __restrict__ beta,
    const float* __restrict__ mean,  const float* __restrict__ var,
    const float* __restrict__ resid, long rBat, int ldr)
{
    __shared__ u16 Al[128][40];   // [m][k], +8 pad (80 B row stride, 16B-aligned)
    __shared__ u16 Bl[128][40];   // [n][k]
    const int bat = blockIdx.z;
    const int m0 = blockIdx.y * 128, n0 = blockIdx.x * 128;
    const int tid = threadIdx.x;
    const int lane = tid & 63, wid = tid >> 6;
    const int wr = wid >> 1, wc = wid & 1;      // 2x2 wave grid, 64x64 per wave
    const int fr = lane & 15, fq = lane >> 4;
    const int sr = tid >> 1, sh = (tid & 1) * 16;   // 2 threads/row, 16 k-cols each

    const u16* Ab = A  + (size_t)bat * aBat + (size_t)(m0 + sr) * lda + sh;
    const u16* Bb = Bt + (size_t)bat * bBat + (size_t)(n0 + sr) * ldb + sh;

    f32x4 acc[4][4];
#pragma unroll
    for (int i = 0; i < 4; i++)
#pragma unroll
        for (int j = 0; j < 4; j++) acc[i][j] = (f32x4){0.f, 0.f, 0.f, 0.f};

    for (int k0 = 0; k0 < K; k0 += 32) {
        u16x8 av0 = *(const u16x8*)(Ab + k0);
        u16x8 av1 = *(const u16x8*)(Ab + k0 + 8);
        u16x8 bv0 = *(const u16x8*)(Bb + k0);
        u16x8 bv1 = *(const u16x8*)(Bb + k0 + 8);
        *(u16x8*)&Al[sr][sh]     = av0;
        *(u16x8*)&Al[sr][sh + 8] = av1;
        *(u16x8*)&Bl[sr][sh]     = bv0;
        *(u16x8*)&Bl[sr][sh + 8] = bv1;
        __syncthreads();
        b8v a[4], b[4];
#pragma unroll
        for (int mi = 0; mi < 4; mi++) a[mi] = *(const b8v*)&Al[wr * 64 + mi * 16 + fr][fq * 8];
#pragma unroll
        for (int ni = 0; ni < 4; ni++) b[ni] = *(const b8v*)&Bl[wc * 64 + ni * 16 + fr][fq * 8];
#pragma unroll
        for (int mi = 0; mi < 4; mi++)
#pragma unroll
            for (int ni = 0; ni < 4; ni++)
                acc[mi][ni] = __builtin_amdgcn_mfma_f32_16x16x32_bf16(a[mi], b[ni], acc[mi][ni], 0, 0, 0);
        __syncthreads();
    }

    const int mbase = m0 + wr * 64, nbase = n0 + wc * 64;
#pragma unroll
    for (int mi = 0; mi < 4; mi++) {
        float esc[4], ead[4];
#pragma unroll
        for (int j = 0; j < 4; j++) {
            int m = mbase + mi * 16 + fq * 4 + j;
            if (EPI == 1) {
                float sc = gamma[m] * rsqrtf(var[m] + 1e-5f);
                esc[j] = sc; ead[j] = beta[m] - mean[m] * sc;
            } else {
                esc[j] = scale; ead[j] = bias ? bias[m] : 0.f;
            }
        }
#pragma unroll
        for (int ni = 0; ni < 4; ni++) {
            f32x4 v = acc[mi][ni];
            const int n = nbase + ni * 16 + fr;
            if (CT) {
                const int mb = mbase + mi * 16 + fq * 4;
                u16x4 pk;
#pragma unroll
                for (int j = 0; j < 4; j++) {
                    float x = v[j] * esc[j] + ead[j];
                    if (EPI == 1) x = x > 0.f ? x : 0.1f * x;
                    pk[j] = f2us(x);
                }
                *(u16x4*)((u16*)Cc + (size_t)bat * cBat + (size_t)n * ldc + mb) = pk;
            } else {
#pragma unroll
                for (int j = 0; j < 4; j++) {
                    int m = mbase + mi * 16 + fq * 4 + j;
                    float x = v[j] * esc[j] + ead[j];
                    if (EPI == 1) x = x > 0.f ? x : 0.1f * x;
                    if (EPI == 2) x += resid[(size_t)bat * rBat + (size_t)m * ldr + n];
                    TC* p = Cc + (size_t)bat * cBat + (size_t)m * ldc + n;
                    if constexpr (sizeof(TC) == 2) *(u16*)p = f2us(x); else *(float*)p = x;
                }
            }
        }
    }
}

// ---------------- conv2 3x3 pad1 as implicit MFMA GEMM (K = C*9 = 2304) ----------------
__global__ __launch_bounds__(256) void conv3x3_mfma(
    const u16* __restrict__ Wt, const u16* __restrict__ X, u16* __restrict__ Y,
    const float* __restrict__ bias)
{
    const int C = 256, P = 4096, K = 2304;
    __shared__ u16 Al[128][40];
    __shared__ u16 Bl[128][40];
    const int bat = blockIdx.z;
    const int m0 = blockIdx.y * 128, n0 = blockIdx.x * 128;
    const int tid = threadIdx.x;
    const int lane = tid & 63, wid = tid >> 6;
    const int wr = wid >> 1, wc = wid & 1;
    const int fr = lane & 15, fq = lane >> 4;
    const int sr = tid >> 1, sh = (tid & 1) * 16;
    const int kk = tid >> 3, ns = tid & 7;

    const u16* Ab = Wt + (size_t)(m0 + sr) * K + sh;
    const u16* Xb = X + (size_t)bat * C * P;

    f32x4 acc[4][4];
#pragma unroll
    for (int i = 0; i < 4; i++)
#pragma unroll
        for (int j = 0; j < 4; j++) acc[i][j] = (f32x4){0.f, 0.f, 0.f, 0.f};

    for (int k0 = 0; k0 < K; k0 += 32) {
        u16x8 av0 = *(const u16x8*)(Ab + k0);
        u16x8 av1 = *(const u16x8*)(Ab + k0 + 8);
        *(u16x8*)&Al[sr][sh]     = av0;
        *(u16x8*)&Al[sr][sh + 8] = av1;
        const int k = k0 + kk;
        const int c = k / 9, tap = k - 9 * c;
        const int dy = tap / 3 - 1, dx = tap - (tap / 3) * 3 - 1;
        const u16* slab = Xb + (size_t)c * P;
#pragma unroll
        for (int i = 0; i < 16; i++) {
            int n = ns + i * 8;
            int p = n0 + n;
            int y = (p >> 6) + dy, x = (p & 63) + dx;
            u16 v = 0;
            if ((unsigned)y < 64u && (unsigned)x < 64u) v = slab[y * 64 + x];
            Bl[n][kk] = v;
        }
        __syncthreads();
        b8v a[4], b[4];
#pragma unroll
        for (int mi = 0; mi < 4; mi++) a[mi] = *(const b8v*)&Al[wr * 64 + mi * 16 + fr][fq * 8];
#pragma unroll
        for (int ni = 0; ni < 4; ni++) b[ni] = *(const b8v*)&Bl[wc * 64 + ni * 16 + fr][fq * 8];
#pragma unroll
        for (int mi = 0; mi < 4; mi++)
#pragma unroll
            for (int ni = 0; ni < 4; ni++)
                acc[mi][ni] = __builtin_amdgcn_mfma_f32_16x16x32_bf16(a[mi], b[ni], acc[mi][ni], 0, 0, 0);
        __syncthreads();
    }

    const int mbase = m0 + wr * 64, nbase = n0 + wc * 64;
#pragma unroll
    for (int mi = 0; mi < 4; mi++) {
        const int mb = mbase + mi * 16 + fq * 4;
        float bb[4];
#pragma unroll
        for (int j = 0; j < 4; j++) bb[j] = bias[mb + j];
#pragma unroll
        for (int ni = 0; ni < 4; ni++) {
            const int n = nbase + ni * 16 + fr;
            u16x4 pk;
#pragma unroll
            for (int j = 0; j < 4; j++) pk[j] = f2us(acc[mi][ni][j] + bb[j]);
            *(u16x4*)&Y[(size_t)bat * P * C + (size_t)n * C + mb] = pk;
        }
    }
}

// ---------------- parallel column-softmax over P ----------------
// Stage 1: per-chunk partial (max, sum). Grid (N/64, PC, B); block 256 = 64 n x 4 pg.
// Each chunk covers P/PC rows; thread walks its pg-strided rows (coalesced 64-n reads).
__global__ __launch_bounds__(256) void softmax_partial(const u16* __restrict__ S,
                                                       float2* __restrict__ part,
                                                       int P, int N, int PC)
{
    const int b = blockIdx.z, chunk = blockIdx.y, n = blockIdx.x * 64 + (threadIdx.x & 63);
    const int pg = threadIdx.x >> 6;
    const int csz = P / PC, p0 = chunk * csz;
    const u16* col = S + ((size_t)b * P + p0) * N + n;
    float m = -3.4e38f, s = 0.f;
    for (int i = pg; i < csz; i += 4) {
        float v = us2f(col[(size_t)i * N]);
        float mn = fmaxf(m, v);
        s = s * __expf(m - mn) + __expf(v - mn);
        m = mn;
    }
    __shared__ float sm[4][64], ss[4][64];
    sm[pg][threadIdx.x & 63] = m;
    ss[pg][threadIdx.x & 63] = s;
    __syncthreads();
    if (pg == 0) {
        const int nl = threadIdx.x & 63;
        float mt = m, st_ = s;
#pragma unroll
        for (int g = 1; g < 4; g++) {
            float mg = sm[g][nl], sg = ss[g][nl];
            float mn = fmaxf(mt, mg);
            st_ = st_ * __expf(mt - mn) + sg * __expf(mg - mn);
            mt = mn;
        }
        part[((size_t)b * PC + chunk) * N + n] = make_float2(mt, st_);
    }
}

// Stage 2: fold PC partials -> st[b][n] = (m, 1/s)
__global__ __launch_bounds__(256) void softmax_merge(const float2* __restrict__ part,
                                                     float2* __restrict__ st, int N, int PC)
{
    const int n = blockIdx.x * 256 + threadIdx.x, b = blockIdx.y;
    const float2* pc = part + (size_t)b * PC * N + n;
    float m = -3.4e38f, s = 0.f;
    for (int c = 0; c < PC; c++) {
        float2 v = pc[(size_t)c * N];
        float mn = fmaxf(m, v.x);
        s = s * __expf(m - mn) + v.y * __expf(v.x - mn);
        m = mn;
    }
    st[(size_t)b * N + n] = make_float2(m, 1.f / s);
}

__global__ __launch_bounds__(256) void softmax_pass2(u16* __restrict__ S,
                                                     const float2* __restrict__ st, int P, int N)
{
    const size_t idx = ((size_t)blockIdx.x * 256 + threadIdx.x) * 8;
    const int n0 = (int)(idx % N);
    const size_t bp = idx / N;
    const int b = (int)(bp / P);
    const float2* sb = st + (size_t)b * N;
    u16x8 v = *(u16x8*)&S[idx];
#pragma unroll
    for (int j = 0; j < 8; j++) {
        float2 ms = sb[n0 + j];
        v[j] = f2us(__expf(us2f(v[j]) - ms.x) * ms.y);
    }
    *(u16x8*)&S[idx] = v;
}

// ---------------- launch ----------------
// Workspace plan — everything inside [0, 88 MiB):
//   [ 0,64)  S [B][P][N]          (written by S-gemm, read softmax+msg)
//   [ 0,16)  xT alias             (dead before S written)
//   [16,16.125) Wq_b alias        (dead before S written)
//   [64,80)  Qt -> msgT           (Qt dead after S-gemm)
//   [80,84)  Kt -> {st, c1/c3/c2 bf16 weights, softmax partials}  (Kt dead after S-gemm)
//   [84,88)  Vb                   (dead after msg-gemm)
//   [ 0,16)  h1  (S dead after msg-gemm);  [16,32) h2T

extern "C" void kernel_launch(void* const* d_in, const int* in_sizes, int n_in,
                              void* d_out, int out_size, void* d_ws, size_t ws_size,
                              hipStream_t stream)
{
    const float* graph = (const float*)d_in[0];   // [8,1024,32]
    const float* image = (const float*)d_in[1];   // [8,256,64,64]
    const float* Wq  = (const float*)d_in[2];
    const float* bq  = (const float*)d_in[3];
    const float* Wk  = (const float*)d_in[4];
    const float* bk  = (const float*)d_in[5];
    const float* Wv  = (const float*)d_in[6];
    const float* bv  = (const float*)d_in[7];
    const float* c1w = (const float*)d_in[8];
    const float* gam = (const float*)d_in[9];
    const float* bet = (const float*)d_in[10];
    const float* mea = (const float*)d_in[11];
    const float* var = (const float*)d_in[12];
    const float* c2w = (const float*)d_in[13];
    const float* c2b = (const float*)d_in[14];
    const float* c3w = (const float*)d_in[15];
    const float* c3b = (const float*)d_in[16];
    float* out = (float*)d_out;

    const int B = 8, C = 256, P = 4096, N = 1024, G = 32;
    const int PC = 16;   // softmax P-chunks
    const size_t MiB = 1024 * 1024, KiB = 1024;
    char* ws = (char*)d_ws;
    u16* S     = (u16*)(ws);                        // [0,64) MiB
    u16* xT    = (u16*)(ws);                        // alias [0,16)
    u16* Wq_b  = (u16*)(ws + 16 * MiB);             // alias [16,16.125)
    u16* Qt    = (u16*)(ws + 64 * MiB);             // [64,80)
    u16* msgT  = Qt;                                // reuse after S-gemm
    float2* st = (float2*)(ws + 80 * MiB);          // 64 KiB (Kt slot, post S-gemm)
    u16* c1w_b = (u16*)(ws + 80 * MiB + 64 * KiB);  // 128 KiB
    u16* c3w_b = (u16*)(ws + 80 * MiB + 192 * KiB); // 128 KiB
    u16* c2w_b = (u16*)(ws + 80 * MiB + 320 * KiB); // 1.125 MiB (< 81.5 MiB)
    float2* part = (float2*)(ws + 82 * MiB);        // 1 MiB  [B][PC][N] (< 84 MiB)
    u16* Kt    = (u16*)(ws + 80 * MiB);             // [80,84), dead after S-gemm
    u16* Vb    = (u16*)(ws + 84 * MiB);             // [84,88)
    u16* h1    = (u16*)(ws);                        // [0,16), S dead after msg
    u16* h2T   = (u16*)(ws + 16 * MiB);             // [16,32)

    // prep
    transpose_cast_x<<<dim3(P / 64, C / 64, B), 256, 0, stream>>>(image, xT, C, P);
    cast_f2b4<<<64,  256, 0, stream>>>(Wq,  Wq_b,  16384);
    // K-proj: Kt[b][n][c] = sum_g graph[b][n][g]*Wk[c][g] + bk[c]
    gemm_any<3, float, float, bf16><<<dim3(C / 64, N / 64, B), 256, 0, stream>>>(
        graph, Wk, (bf16*)Kt, N, C, G,
        G, 1, (long)N * G,   1, G, 0,   C, 1, (long)N * C, 1.f, bk);
    // V-proj: Vb[b][c][n] = sum_g Wv[c][g]*graph[b][n][g] + bv[c]
    gemm_any<0, float, float, bf16><<<dim3(N / 64, C / 64, B), 256, 0, stream>>>(
        Wv, graph, (bf16*)Vb, C, N, G,
        G, 1, 0,   1, G, (long)N * G,   N, 1, (long)C * N, 1.f, bv);

    // Q: Qt[b][p][c] = sum_k Wq[c][k]*xT[b][p][k] + bq[c]    (CT store)
    gemm_mfma<0, true, u16><<<dim3(P / 128, C / 128, B), 256, 0, stream>>>(
        Wq_b, xT, Qt, C, P, C, C, C, C,
        0, (long)P * C, (long)P * C, 1.f, bq,
        nullptr, nullptr, nullptr, nullptr, nullptr, 0, 0);
    // S[b][p][n] = (1/16) sum_c Qt[p][c]*Kt[n][c]
    gemm_mfma<0, false, u16><<<dim3(N / 128, P / 128, B), 256, 0, stream>>>(
        Qt, Kt, S, P, N, C, C, C, N,
        (long)P * C, (long)N * C, (long)P * N, 0.0625f, nullptr,
        nullptr, nullptr, nullptr, nullptr, nullptr, 0, 0);
    // Kt slot now dead: cast conv weights into it
    cast_f2b4<<<64,  256, 0, stream>>>(c1w, c1w_b, 16384);
    cast_f2b4<<<64,  256, 0, stream>>>(c3w, c3w_b, 16384);
    cast_f2b4<<<576, 256, 0, stream>>>(c2w, c2w_b, 147456);
    // parallel softmax over p
    softmax_partial<<<dim3(N / 64, PC, B), 256, 0, stream>>>(S, part, P, N, PC);
    softmax_merge<<<dim3(N / 256, B), 256, 0, stream>>>(part, st, N, PC);
    softmax_pass2<<<dim3((int)(((size_t)B * P * N / 8) / 256)), 256, 0, stream>>>(S, st, P, N);
    // msgT[b][p][c] = sum_n Vb[c][n]*att[p][n]   (CT store, into Qt slot)
    gemm_mfma<0, true, u16><<<dim3(P / 128, C / 128, B), 256, 0, stream>>>(
        Vb, S, msgT, C, P, N, N, N, C,
        (long)C * N, (long)P * N, (long)P * C, 1.f, nullptr,
        nullptr, nullptr, nullptr, nullptr, nullptr, 0, 0);
    // h1[b][c][p] = LeakyReLU(BN(conv1(msg)))   (into S slot [0,16))
    gemm_mfma<1, false, u16><<<dim3(P / 128, C / 128, B), 256, 0, stream>>>(
        c1w_b, msgT, h1, C, P, C, C, C, P,
        0, (long)P * C, (long)C * P, 1.f, nullptr,
        gam, bet, mea, var, nullptr, 0, 0);
    // h2T[b][p][c] = conv2 3x3(h1) + c2b   (into S slot [16,32))
    conv3x3_mfma<<<dim3(P / 128, C / 128, B), 256, 0, stream>>>(c2w_b, h1, h2T, c2b);
    // out[b][c][p] = image + conv3(h2) + c3b
    gemm_mfma<2, false, float><<<dim3(P / 128, C / 128, B), 256, 0, stream>>>(
        c3w_b, h2T, out, C, P, C, C, C, P,
        0, (long)P * C, (long)C * P, 1.f, c3b,
        nullptr, nullptr, nullptr, nullptr, image, (long)C * P, P);
}

// Round 7
// 293.397 us; speedup vs baseline: 9.3601x; 1.4067x over previous
//
#include <hip/hip_runtime.h>
#include <hip/hip_bf16.h>

typedef __hip_bfloat16 bf16;
typedef unsigned short u16;
typedef __attribute__((ext_vector_type(8))) short  b8v;    // 8 bf16 bits (4 VGPR) MFMA operand
typedef __attribute__((ext_vector_type(8))) unsigned short u16x8;
typedef __attribute__((ext_vector_type(4))) unsigned short u16x4;
typedef __attribute__((ext_vector_type(4))) float f32x4;

static __device__ __forceinline__ float us2f(u16 s) {
    unsigned int u = ((unsigned int)s) << 16;
    return __builtin_bit_cast(float, u);
}
static __device__ __forceinline__ u16 f2us(float x) {
    union { bf16 h; u16 s; } v; v.h = __float2bfloat16(x); return v.s;
}
static __device__ __forceinline__ float b2f(bf16 x) { return __bfloat162float(x); }
static __device__ __forceinline__ bf16 f2b(float x) { return __float2bfloat16(x); }
static __device__ __forceinline__ float toF(float x) { return x; }
static __device__ __forceinline__ float toF(bf16 x)  { return b2f(x); }
static __device__ __forceinline__ void stor(float* p, float v) { *p = v; }
static __device__ __forceinline__ void stor(bf16* p,  float v) { *p = f2b(v); }

// ---------------- small prep kernels ----------------

__global__ __launch_bounds__(256) void cast_f2b4(const float* __restrict__ src,
                                                 u16* __restrict__ dst, int n4)
{
    int i = blockIdx.x * 256 + threadIdx.x;
    if (i < n4) {
        float4 v = ((const float4*)src)[i];
        u16x4 o = { f2us(v.x), f2us(v.y), f2us(v.z), f2us(v.w) };
        ((u16x4*)dst)[i] = o;
    }
}

// conv2 weights [O=256][C=256][3][3] fp32 -> wr[o][k] bf16 with k = tap*256 + c
__global__ __launch_bounds__(256) void repack_w2(const float* __restrict__ src,
                                                 u16* __restrict__ dst)
{
    int idx = blockIdx.x * 256 + threadIdx.x;       // 256*2304 total
    int o = idx / 2304, k = idx - o * 2304;
    int tap = k >> 8, c = k & 255;
    dst[idx] = f2us(src[(o * 256 + c) * 9 + tap]);
}

// x[b][c][p] f32 -> xT[b][p][c] bf16, 64x64 LDS tiles
// row stride 72 u16 = 144 B keeps the u16x8 (ds_read_b128) reads 16B-aligned
__global__ __launch_bounds__(256) void transpose_cast_x(const float* __restrict__ x,
                                                        u16* __restrict__ xT, int C, int P)
{
    __shared__ u16 t[64][72];
    const int b = blockIdx.z, c0 = blockIdx.y * 64, p0 = blockIdx.x * 64;
    const int tid = threadIdx.x;
    const int r = tid >> 2, q = tid & 3;
    const float* src = x + ((size_t)b * C + c0 + r) * P + p0 + q * 16;
#pragma unroll
    for (int i = 0; i < 16; i++) t[q * 16 + i][r] = f2us(src[i]);
    __syncthreads();
    u16* dst = xT + ((size_t)b * P + p0 + r) * C + c0 + q * 16;
    *(u16x8*)dst       = *(u16x8*)&t[r][q * 16];
    *(u16x8*)(dst + 8) = *(u16x8*)&t[r][q * 16 + 8];
}

// ---------------- fp32-input VALU GEMM (tiny K/V projections only) ----------------
// EPI: 0 bias per m; 3 bias per n
template<int EPI, typename TA, typename TB, typename TC>
__global__ __launch_bounds__(256) void gemm_any(
    const TA* __restrict__ A, const TB* __restrict__ B, TC* __restrict__ C,
    int M, int Nn, int Kd,
    long saM, long saK, long aB,
    long sbK, long sbN, long bB,
    long scM, long scN, long cB,
    float scale, const float* __restrict__ bias)
{
    __shared__ float As[16][65];
    __shared__ float Bs[16][65];
    const int b  = blockIdx.z;
    const TA* Ab = A + (long)b * aB;
    const TB* Bb = B + (long)b * bB;
    const int m0 = blockIdx.y * 64, n0 = blockIdx.x * 64;
    const int tid = threadIdx.x;
    const int tx = tid & 15, ty = tid >> 4;
    const bool kfA = (saK == 1);
    const bool nfB = (sbN == 1);
    float acc[4][4] = {};

    for (int k0 = 0; k0 < Kd; k0 += 16) {
#pragma unroll
        for (int i = 0; i < 4; i++) {
            int idx = tid + i * 256; int mm, kk;
            if (kfA) { kk = idx & 15; mm = idx >> 4; }
            else     { mm = idx & 63; kk = idx >> 6; }
            As[kk][mm] = toF(Ab[(long)(m0 + mm) * saM + (long)(k0 + kk) * saK]);
        }
#pragma unroll
        for (int i = 0; i < 4; i++) {
            int idx = tid + i * 256; int nn, kk;
            if (nfB) { nn = idx & 63; kk = idx >> 6; }
            else     { kk = idx & 15; nn = idx >> 4; }
            Bs[kk][nn] = toF(Bb[(long)(k0 + kk) * sbK + (long)(n0 + nn) * sbN]);
        }
        __syncthreads();
#pragma unroll
        for (int kk = 0; kk < 16; kk++) {
            float a[4], bb[4];
#pragma unroll
            for (int i = 0; i < 4; i++) a[i]  = As[kk][ty * 4 + i];
#pragma unroll
            for (int j = 0; j < 4; j++) bb[j] = Bs[kk][tx * 4 + j];
#pragma unroll
            for (int i = 0; i < 4; i++)
#pragma unroll
                for (int j = 0; j < 4; j++) acc[i][j] += a[i] * bb[j];
        }
        __syncthreads();
    }
#pragma unroll
    for (int i = 0; i < 4; i++) {
        int m = m0 + ty * 4 + i;
        float add0 = (EPI == 0 && bias) ? bias[m] : 0.f;
#pragma unroll
        for (int j = 0; j < 4; j++) {
            int n = n0 + tx * 4 + j;
            float v = acc[i][j] * scale + add0;
            if (EPI == 3 && bias) v += bias[n];
            stor(&C[(long)b * cB + (long)m * scM + (long)n * scN], v);
        }
    }
}

// ---------------- MFMA GEMM: C[m][n] = epi( scale * sum_k A[m][k] * Bt[n][k] ) ----------------
// Register-prefetch pipeline: next K-step's loads issue under the current MFMAs.
template<int EPI, bool CT, typename TC>
__global__ __launch_bounds__(256) void gemm_mfma(
    const u16* __restrict__ A, const u16* __restrict__ Bt, TC* __restrict__ Cc,
    int M, int N, int K, int lda, int ldb, int ldc,
    long aBat, long bBat, long cBat,
    float scale, const float* __restrict__ bias,
    const float* __restrict__ gamma, const float* __restrict__ beta,
    const float* __restrict__ mean,  const float* __restrict__ var,
    const float* __restrict__ resid, long rBat, int ldr)
{
    __shared__ u16 Al[128][40];   // [m][k], +8 pad (80 B row stride, 16B-aligned)
    __shared__ u16 Bl[128][40];   // [n][k]
    const int bat = blockIdx.z;
    const int m0 = blockIdx.y * 128, n0 = blockIdx.x * 128;
    const int tid = threadIdx.x;
    const int lane = tid & 63, wid = tid >> 6;
    const int wr = wid >> 1, wc = wid & 1;      // 2x2 wave grid, 64x64 per wave
    const int fr = lane & 15, fq = lane >> 4;
    const int sr = tid >> 1, sh = (tid & 1) * 16;   // 2 threads/row, 16 k-cols each

    const u16* Ab = A  + (size_t)bat * aBat + (size_t)(m0 + sr) * lda + sh;
    const u16* Bb = Bt + (size_t)bat * bBat + (size_t)(n0 + sr) * ldb + sh;

    f32x4 acc[4][4];
#pragma unroll
    for (int i = 0; i < 4; i++)
#pragma unroll
        for (int j = 0; j < 4; j++) acc[i][j] = (f32x4){0.f, 0.f, 0.f, 0.f};

    u16x8 av0 = *(const u16x8*)(Ab);
    u16x8 av1 = *(const u16x8*)(Ab + 8);
    u16x8 bv0 = *(const u16x8*)(Bb);
    u16x8 bv1 = *(const u16x8*)(Bb + 8);

    for (int k0 = 0; k0 < K; k0 += 32) {
        *(u16x8*)&Al[sr][sh]     = av0;
        *(u16x8*)&Al[sr][sh + 8] = av1;
        *(u16x8*)&Bl[sr][sh]     = bv0;
        *(u16x8*)&Bl[sr][sh + 8] = bv1;
        __syncthreads();
        if (k0 + 32 < K) {
            av0 = *(const u16x8*)(Ab + k0 + 32);
            av1 = *(const u16x8*)(Ab + k0 + 40);
            bv0 = *(const u16x8*)(Bb + k0 + 32);
            bv1 = *(const u16x8*)(Bb + k0 + 40);
        }
        b8v a[4], b[4];
#pragma unroll
        for (int mi = 0; mi < 4; mi++) a[mi] = *(const b8v*)&Al[wr * 64 + mi * 16 + fr][fq * 8];
#pragma unroll
        for (int ni = 0; ni < 4; ni++) b[ni] = *(const b8v*)&Bl[wc * 64 + ni * 16 + fr][fq * 8];
#pragma unroll
        for (int mi = 0; mi < 4; mi++)
#pragma unroll
            for (int ni = 0; ni < 4; ni++)
                acc[mi][ni] = __builtin_amdgcn_mfma_f32_16x16x32_bf16(a[mi], b[ni], acc[mi][ni], 0, 0, 0);
        __syncthreads();
    }

    const int mbase = m0 + wr * 64, nbase = n0 + wc * 64;
#pragma unroll
    for (int mi = 0; mi < 4; mi++) {
        float esc[4], ead[4];
#pragma unroll
        for (int j = 0; j < 4; j++) {
            int m = mbase + mi * 16 + fq * 4 + j;
            if (EPI == 1) {
                float sc = gamma[m] * rsqrtf(var[m] + 1e-5f);
                esc[j] = sc; ead[j] = beta[m] - mean[m] * sc;
            } else {
                esc[j] = scale; ead[j] = bias ? bias[m] : 0.f;
            }
        }
#pragma unroll
        for (int ni = 0; ni < 4; ni++) {
            f32x4 v = acc[mi][ni];
            const int n = nbase + ni * 16 + fr;
            if (CT) {
                const int mb = mbase + mi * 16 + fq * 4;
                u16x4 pk;
#pragma unroll
                for (int j = 0; j < 4; j++) {
                    float x = v[j] * esc[j] + ead[j];
                    if (EPI == 1) x = x > 0.f ? x : 0.1f * x;
                    pk[j] = f2us(x);
                }
                *(u16x4*)((u16*)Cc + (size_t)bat * cBat + (size_t)n * ldc + mb) = pk;
            } else {
#pragma unroll
                for (int j = 0; j < 4; j++) {
                    int m = mbase + mi * 16 + fq * 4 + j;
                    float x = v[j] * esc[j] + ead[j];
                    if (EPI == 1) x = x > 0.f ? x : 0.1f * x;
                    if (EPI == 2) x += resid[(size_t)bat * rBat + (size_t)m * ldr + n];
                    TC* p = Cc + (size_t)bat * cBat + (size_t)m * ldc + n;
                    if constexpr (sizeof(TC) == 2) *(u16*)p = f2us(x); else *(float*)p = x;
                }
            }
        }
    }
}

// ---------------- conv2 3x3 pad1, tap-major implicit MFMA GEMM ----------------
// A = wr [256][2304] (k = tap*256 + c); X = h1 [B][256][4096]; Y = h2T [B][4096][256]
// K-step of 32 = one tap x 32 channels -> wave-uniform shift, coalesced staging.
__global__ __launch_bounds__(256) void conv3x3_mfma(
    const u16* __restrict__ Wt, const u16* __restrict__ X, u16* __restrict__ Y,
    const float* __restrict__ bias)
{
    const int C = 256, P = 4096, K = 2304;
    __shared__ u16 Al[128][40];
    __shared__ u16 Bl[128][40];
    const int bat = blockIdx.z;
    const int m0 = blockIdx.y * 128, n0 = blockIdx.x * 128;
    const int tid = threadIdx.x;
    const int lane = tid & 63, wid = tid >> 6;
    const int wr = wid >> 1, wc = wid & 1;
    const int fr = lane & 15, fq = lane >> 4;
    const int sr = tid >> 1, sh = (tid & 1) * 16;     // A staging
    const int bn = tid & 127;                          // B staging: pixel in tile
    const int bx = bn & 63, brr = bn >> 6;
    const int bhalf = tid >> 7;
    const int y0 = n0 >> 6;

    const u16* Ab = Wt + (size_t)(m0 + sr) * K + sh;
    const u16* Xb = X + (size_t)bat * C * P;

    f32x4 acc[4][4];
#pragma unroll
    for (int i = 0; i < 4; i++)
#pragma unroll
        for (int j = 0; j < 4; j++) acc[i][j] = (f32x4){0.f, 0.f, 0.f, 0.f};

    u16x8 areg0, areg1, breg[2];

    auto loadA = [&](int k0) {
        areg0 = *(const u16x8*)(Ab + k0);
        areg1 = *(const u16x8*)(Ab + k0 + 8);
    };
    auto loadB = [&](int k0) {
        const int tap = k0 >> 8, c0k = k0 & 255;
        const int dy = tap / 3 - 1, dxv = tap - (tap / 3) * 3 - 1;
        const int y = y0 + brr + dy, xs = bx + dxv;
        const bool ok = ((unsigned)y < 64u) && ((unsigned)xs < 64u);
        const int off = ok ? (y * 64 + xs) : 0;   // clamped, always in-bounds
#pragma unroll
        for (int j = 0; j < 2; j++) {
            const int g8 = j * 2 + bhalf;          // channel group of 8
            const u16* src = Xb + (size_t)(c0k + g8 * 8) * P + off;
            u16x8 v;
#pragma unroll
            for (int l = 0; l < 8; l++) v[l] = src[(size_t)l * P];
            if (!ok) v = (u16x8){0, 0, 0, 0, 0, 0, 0, 0};
            breg[j] = v;
        }
    };

    loadA(0); loadB(0);

    for (int k0 = 0; k0 < K; k0 += 32) {
        *(u16x8*)&Al[sr][sh]     = areg0;
        *(u16x8*)&Al[sr][sh + 8] = areg1;
        *(u16x8*)&Bl[bn][bhalf * 8]      = breg[0];   // g8 = bhalf
        *(u16x8*)&Bl[bn][16 + bhalf * 8] = breg[1];   // g8 = 2 + bhalf
        __syncthreads();
        if (k0 + 32 < K) { loadA(k0 + 32); loadB(k0 + 32); }
        b8v a[4], b[4];
#pragma unroll
        for (int mi = 0; mi < 4; mi++) a[mi] = *(const b8v*)&Al[wr * 64 + mi * 16 + fr][fq * 8];
#pragma unroll
        for (int ni = 0; ni < 4; ni++) b[ni] = *(const b8v*)&Bl[wc * 64 + ni * 16 + fr][fq * 8];
#pragma unroll
        for (int mi = 0; mi < 4; mi++)
#pragma unroll
            for (int ni = 0; ni < 4; ni++)
                acc[mi][ni] = __builtin_amdgcn_mfma_f32_16x16x32_bf16(a[mi], b[ni], acc[mi][ni], 0, 0, 0);
        __syncthreads();
    }

    const int mbase = m0 + wr * 64, nbase = n0 + wc * 64;
#pragma unroll
    for (int mi = 0; mi < 4; mi++) {
        const int mb = mbase + mi * 16 + fq * 4;
        float bb[4];
#pragma unroll
        for (int j = 0; j < 4; j++) bb[j] = bias[mb + j];
#pragma unroll
        for (int ni = 0; ni < 4; ni++) {
            const int n = nbase + ni * 16 + fr;
            u16x4 pk;
#pragma unroll
            for (int j = 0; j < 4; j++) pk[j] = f2us(acc[mi][ni][j] + bb[j]);
            *(u16x4*)&Y[(size_t)bat * P * C + (size_t)n * C + mb] = pk;
        }
    }
}

// ---------------- parallel column-softmax over P ----------------
__global__ __launch_bounds__(256) void softmax_partial(const u16* __restrict__ S,
                                                       float2* __restrict__ part,
                                                       int P, int N, int PC)
{
    const int b = blockIdx.z, chunk = blockIdx.y, n = blockIdx.x * 64 + (threadIdx.x & 63);
    const int pg = threadIdx.x >> 6;
    const int csz = P / PC, p0 = chunk * csz;
    const u16* col = S + ((size_t)b * P + p0) * N + n;
    float m = -3.4e38f, s = 0.f;
    for (int i = pg; i < csz; i += 4) {
        float v = us2f(col[(size_t)i * N]);
        float mn = fmaxf(m, v);
        s = s * __expf(m - mn) + __expf(v - mn);
        m = mn;
    }
    __shared__ float sm[4][64], ss[4][64];
    sm[pg][threadIdx.x & 63] = m;
    ss[pg][threadIdx.x & 63] = s;
    __syncthreads();
    if (pg == 0) {
        const int nl = threadIdx.x & 63;
        float mt = m, st_ = s;
#pragma unroll
        for (int g = 1; g < 4; g++) {
            float mg = sm[g][nl], sg = ss[g][nl];
            float mn = fmaxf(mt, mg);
            st_ = st_ * __expf(mt - mn) + sg * __expf(mg - mn);
            mt = mn;
        }
        part[((size_t)b * PC + chunk) * N + n] = make_float2(mt, st_);
    }
}

__global__ __launch_bounds__(256) void softmax_merge(const float2* __restrict__ part,
                                                     float2* __restrict__ st, int N, int PC)
{
    const int n = blockIdx.x * 256 + threadIdx.x, b = blockIdx.y;
    const float2* pc = part + (size_t)b * PC * N + n;
    float m = -3.4e38f, s = 0.f;
    for (int c = 0; c < PC; c++) {
        float2 v = pc[(size_t)c * N];
        float mn = fmaxf(m, v.x);
        s = s * __expf(m - mn) + v.y * __expf(v.x - mn);
        m = mn;
    }
    st[(size_t)b * N + n] = make_float2(m, 1.f / s);
}

__global__ __launch_bounds__(256) void softmax_pass2(u16* __restrict__ S,
                                                     const float2* __restrict__ st, int P, int N)
{
    const size_t idx = ((size_t)blockIdx.x * 256 + threadIdx.x) * 8;
    const int n0 = (int)(idx % N);
    const size_t bp = idx / N;
    const int b = (int)(bp / P);
    const float2* sb = st + (size_t)b * N;
    u16x8 v = *(u16x8*)&S[idx];
#pragma unroll
    for (int j = 0; j < 8; j++) {
        float2 ms = sb[n0 + j];
        v[j] = f2us(__expf(us2f(v[j]) - ms.x) * ms.y);
    }
    *(u16x8*)&S[idx] = v;
}

// ---------------- launch ----------------
// Workspace plan — everything inside [0, 88 MiB):
//   [ 0,64)  S [B][P][N]          (written by S-gemm, read softmax+msg)
//   [ 0,16)  xT alias             (dead before S written)
//   [16,16.125) Wq_b alias        (dead before S written)
//   [64,80)  Qt -> msgT           (Qt dead after S-gemm)
//   [80,84)  Kt -> {st, c1/c3 bf16, repacked c2w, softmax partials}  (Kt dead after S-gemm)
//   [84,88)  Vb                   (dead after msg-gemm)
//   [ 0,16)  h1  (S dead after msg-gemm);  [16,32) h2T

extern "C" void kernel_launch(void* const* d_in, const int* in_sizes, int n_in,
                              void* d_out, int out_size, void* d_ws, size_t ws_size,
                              hipStream_t stream)
{
    const float* graph = (const float*)d_in[0];   // [8,1024,32]
    const float* image = (const float*)d_in[1];   // [8,256,64,64]
    const float* Wq  = (const float*)d_in[2];
    const float* bq  = (const float*)d_in[3];
    const float* Wk  = (const float*)d_in[4];
    const float* bk  = (const float*)d_in[5];
    const float* Wv  = (const float*)d_in[6];
    const float* bv  = (const float*)d_in[7];
    const float* c1w = (const float*)d_in[8];
    const float* gam = (const float*)d_in[9];
    const float* bet = (const float*)d_in[10];
    const float* mea = (const float*)d_in[11];
    const float* var = (const float*)d_in[12];
    const float* c2w = (const float*)d_in[13];
    const float* c2b = (const float*)d_in[14];
    const float* c3w = (const float*)d_in[15];
    const float* c3b = (const float*)d_in[16];
    float* out = (float*)d_out;

    const int B = 8, C = 256, P = 4096, N = 1024, G = 32;
    const int PC = 16;   // softmax P-chunks
    const size_t MiB = 1024 * 1024, KiB = 1024;
    char* ws = (char*)d_ws;
    u16* S     = (u16*)(ws);                        // [0,64) MiB
    u16* xT    = (u16*)(ws);                        // alias [0,16)
    u16* Wq_b  = (u16*)(ws + 16 * MiB);             // alias [16,16.125)
    u16* Qt    = (u16*)(ws + 64 * MiB);             // [64,80)
    u16* msgT  = Qt;                                // reuse after S-gemm
    float2* st = (float2*)(ws + 80 * MiB);          // 64 KiB (Kt slot, post S-gemm)
    u16* c1w_b = (u16*)(ws + 80 * MiB + 64 * KiB);  // 128 KiB
    u16* c3w_b = (u16*)(ws + 80 * MiB + 192 * KiB); // 128 KiB
    u16* c2w_b = (u16*)(ws + 80 * MiB + 320 * KiB); // 1.125 MiB (< 81.5 MiB)
    float2* part = (float2*)(ws + 82 * MiB);        // 1 MiB  [B][PC][N] (< 84 MiB)
    u16* Kt    = (u16*)(ws + 80 * MiB);             // [80,84), dead after S-gemm
    u16* Vb    = (u16*)(ws + 84 * MiB);             // [84,88)
    u16* h1    = (u16*)(ws);                        // [0,16), S dead after msg
    u16* h2T   = (u16*)(ws + 16 * MiB);             // [16,32)

    // prep
    transpose_cast_x<<<dim3(P / 64, C / 64, B), 256, 0, stream>>>(image, xT, C, P);
    cast_f2b4<<<64,  256, 0, stream>>>(Wq,  Wq_b,  16384);
    // K-proj: Kt[b][n][c] = sum_g graph[b][n][g]*Wk[c][g] + bk[c]
    gemm_any<3, float, float, bf16><<<dim3(C / 64, N / 64, B), 256, 0, stream>>>(
        graph, Wk, (bf16*)Kt, N, C, G,
        G, 1, (long)N * G,   1, G, 0,   C, 1, (long)N * C, 1.f, bk);
    // V-proj: Vb[b][c][n] = sum_g Wv[c][g]*graph[b][n][g] + bv[c]
    gemm_any<0, float, float, bf16><<<dim3(N / 64, C / 64, B), 256, 0, stream>>>(
        Wv, graph, (bf16*)Vb, C, N, G,
        G, 1, 0,   1, G, (long)N * G,   N, 1, (long)C * N, 1.f, bv);

    // Q: Qt[b][p][c] = sum_k Wq[c][k]*xT[b][p][k] + bq[c]    (CT store)
    gemm_mfma<0, true, u16><<<dim3(P / 128, C / 128, B), 256, 0, stream>>>(
        Wq_b, xT, Qt, C, P, C, C, C, C,
        0, (long)P * C, (long)P * C, 1.f, bq,
        nullptr, nullptr, nullptr, nullptr, nullptr, 0, 0);
    // S[b][p][n] = (1/16) sum_c Qt[p][c]*Kt[n][c]
    gemm_mfma<0, false, u16><<<dim3(N / 128, P / 128, B), 256, 0, stream>>>(
        Qt, Kt, S, P, N, C, C, C, N,
        (long)P * C, (long)N * C, (long)P * N, 0.0625f, nullptr,
        nullptr, nullptr, nullptr, nullptr, nullptr, 0, 0);
    // Kt slot now dead: conv weights into it
    cast_f2b4<<<64,   256, 0, stream>>>(c1w, c1w_b, 16384);
    cast_f2b4<<<64,   256, 0, stream>>>(c3w, c3w_b, 16384);
    repack_w2<<<2304, 256, 0, stream>>>(c2w, c2w_b);
    // parallel softmax over p
    softmax_partial<<<dim3(N / 64, PC, B), 256, 0, stream>>>(S, part, P, N, PC);
    softmax_merge<<<dim3(N / 256, B), 256, 0, stream>>>(part, st, N, PC);
    softmax_pass2<<<dim3((int)(((size_t)B * P * N / 8) / 256)), 256, 0, stream>>>(S, st, P, N);
    // msgT[b][p][c] = sum_n Vb[c][n]*att[p][n]   (CT store, into Qt slot)
    gemm_mfma<0, true, u16><<<dim3(P / 128, C / 128, B), 256, 0, stream>>>(
        Vb, S, msgT, C, P, N, N, N, C,
        (long)C * N, (long)P * N, (long)P * C, 1.f, nullptr,
        nullptr, nullptr, nullptr, nullptr, nullptr, 0, 0);
    // h1[b][c][p] = LeakyReLU(BN(conv1(msg)))   (into S slot [0,16))
    gemm_mfma<1, false, u16><<<dim3(P / 128, C / 128, B), 256, 0, stream>>>(
        c1w_b, msgT, h1, C, P, C, C, C, P,
        0, (long)P * C, (long)C * P, 1.f, nullptr,
        gam, bet, mea, var, nullptr, 0, 0);
    // h2T[b][p][c] = conv2 3x3(h1) + c2b   (into S slot [16,32))
    conv3x3_mfma<<<dim3(P / 128, C / 128, B), 256, 0, stream>>>(c2w_b, h1, h2T, c2b);
    // out[b][c][p] = image + conv3(h2) + c3b
    gemm_mfma<2, false, float><<<dim3(P / 128, C / 128, B), 256, 0, stream>>>(
        c3w_b, h2T, out, C, P, C, C, C, P,
        0, (long)P * C, (long)C * P, 1.f, c3b,
        nullptr, nullptr, nullptr, nullptr, image, (long)C * P, P);
}